// Round 4
// baseline (296.303 us; speedup 1.0000x reference)
//
#include <hip/hip_runtime.h>
#include <hip/hip_bf16.h>

// ---------------------------------------------------------------------------
// NHRepNet fused forward, Round 18: 4-wave blocks, Gch=4 (halve LDS-B stream).
//
// Established (R1-R17):
//  - R14 (phase-serial): 115us = LDS/mfma phase ~61 + epi phase ~54, serial.
//  - R17 (kk-sliced A/B stagger, clean A/B vs R14): 103.4us, Mfma+VALU 87%.
//    INTERLEAVE IS REAL. But afr depth-1 prefetch + 48 acc spilled ~6MB
//    (WRITE 3.5->9.9MB): win = overlap - spill tax.
//  - LDS-B stream = (waves reading each row) x 512B/row/layer. Gch=8 -> 3GB
//    (~57us). A-stream 1.56GB L2 (~45% util). VALU ~54us. MFMA ~35us.
//
// R18: 256-thr blocks (4 waves), wave owns 64 out-ch (4 strips), same 96-pt
// tile, same stagger+slice retirement:
//  - LDS-B halves (4 readers/row): 3GB -> 1.5GB (~28us stream).
//  - A-traffic UNCHANGED (W read once per region: 4 waves x 32KB).
//  - B-reuse/wave doubles: 12 MFMA : 3 ds_read per kk.
//  - acc[4][3]=48 regs (same as R17); afr prefetch DROPPED (spill suspect);
//    __launch_bounds__(256,3): occupancy is LDS-bound (3 blk/CU = 12 w/CU,
//    same as today) so reg budget ~170 is free spill insurance.
// Gates: WRITE<=5MB (no spill), dur 82-90us, Mfma+VALU >= 100% combined.
// Null (dur~100, clean) -> R19 attacks VALU (poly-log softplus).
// ---------------------------------------------------------------------------

using bf16x8 = __attribute__((ext_vector_type(8))) __bf16;
using f32x4  = __attribute__((ext_vector_type(4))) float;

#define LDA 264   // padded activation row stride (bf16); 528B = 16B-aligned,
                  // row-to-row bank step 4 -> 2-way (free tier) on b128 reads

#define OFFW0 0
#define OFFW1 8192
#define OFFW7 401408
#define WSB_BYTE_OFF 811008   // fp32 bias region
#define OFFB7 1792            // L0..L6 at l*256; L7 at 1792 (16 floats, padded)

#define SCALE_T2 144.26950408889634f      // 100*log2(e)
#define INV_SQRT2 0.70710678118654752f
#define LN2_100 0.0069314718055994531f    // ln2/100

__device__ __forceinline__ float fast_exp2(float x) {
#if __has_builtin(__builtin_amdgcn_exp2f)
    return __builtin_amdgcn_exp2f(x);
#else
    return exp2f(x);
#endif
}
__device__ __forceinline__ float fast_log2(float x) {
#if __has_builtin(__builtin_amdgcn_logf)
    return __builtin_amdgcn_logf(x);
#else
    return log2f(x);
#endif
}

// a2 = max(t2,0) + log2(1 + 2^-|t2|)   (t2-domain; scales folded into weights)
__device__ __forceinline__ float softplus_t2(float t2) {
    float e = fast_exp2(-fabsf(t2));
    float l = fast_log2(1.0f + e);
    return fmaxf(t2, 0.0f) + l;
}

__device__ __forceinline__ unsigned short bf16_rne(float f) {
    unsigned int u = __float_as_uint(f);
    unsigned int r = u + 0x7FFFu + ((u >> 16) & 1u);
    return (unsigned short)(r >> 16);
}

// ---------------------------------------------------------------------------
// Plain MFMA half (layer 0 only, KK=1). Wave owns ch [wave*64, wave*64+64).
// ---------------------------------------------------------------------------
template <int KK, int NTG>
__device__ __forceinline__ void mfma_group(
    const unsigned short* __restrict__ wfrag,
    const float* __restrict__ bias,
    const unsigned short* act,
    f32x4 (&acc)[4][NTG], int wave, int lane)
{
    const int quad = lane >> 4;
    const int l15  = lane & 15;

#pragma unroll
    for (int i = 0; i < 4; ++i) {
        const int chb = (wave * 4 + i) * 16 + quad * 4;
        const float4 b4 = *(const float4*)(bias + chb);
#pragma unroll
        for (int nt = 0; nt < NTG; ++nt)
            acc[i][nt] = f32x4{b4.x, b4.y, b4.z, b4.w};
    }

    const unsigned short* wbase = wfrag + (wave * 4 * KK * 64 + lane) * 8;

#pragma unroll
    for (int kk = 0; kk < KK; ++kk) {
        bf16x8 bfr[NTG];
#pragma unroll
        for (int nt = 0; nt < NTG; ++nt)
            bfr[nt] = *(const bf16x8*)(act + (nt * 16 + l15) * LDA + kk * 32 + quad * 8);
#pragma unroll
        for (int i = 0; i < 4; ++i) {
            bf16x8 afr = *(const bf16x8*)(wbase + (i * KK + kk) * 512);
#pragma unroll
            for (int nt = 0; nt < NTG; ++nt)
                acc[i][nt] = __builtin_amdgcn_mfma_f32_16x16x32_bf16(afr, bfr[nt], acc[i][nt], 0, 0, 0);
        }
    }
}

// Full epilogue of a group (used where no mfma to hide under).
template <int NTG>
__device__ __forceinline__ void epi_group_full(
    f32x4 (&acc)[4][NTG], unsigned short* act, const float* xst,
    int wave, int lane, bool splice)
{
    const int quad = lane >> 4;
    const int l15  = lane & 15;
#pragma unroll
    for (int i = 0; i < 4; ++i) {
        const int chb = (wave * 4 + i) * 16 + quad * 4;
#pragma unroll
        for (int nt = 0; nt < NTG; ++nt) {
            const int pt = nt * 16 + l15;
            float vv[4];
#pragma unroll
            for (int r = 0; r < 4; ++r)
                vv[r] = softplus_t2(acc[i][nt][r]);
            if (splice && chb == 252) {
                vv[1] = xst[pt * 4 + 0];
                vv[2] = xst[pt * 4 + 1];
                vv[3] = xst[pt * 4 + 2];
            }
            __hip_bfloat162 p01 = __float22bfloat162_rn(float2{vv[0], vv[1]});
            __hip_bfloat162 p23 = __float22bfloat162_rn(float2{vv[2], vv[3]});
            uint2 pk;
            pk.x = *(unsigned int*)&p01;
            pk.y = *(unsigned int*)&p23;
            *(uint2*)(act + pt * LDA + chb) = pk;
        }
    }
}

// ---------------------------------------------------------------------------
// Staggered region: build accX = W.actX + b while retiring accY (other
// group's previous-layer preacts) 1-2 slices per kk step. Slice VALU sits
// between bfr ds_reads / afr loads and the 4*NTG MFMAs (load-wait shadow).
// Slices: S = 4*NTG total; kk retires slice kk (kk < min(S,8)) and slice
// 8+kk (kk < S-8). All indices compile-time under full unroll.
// ---------------------------------------------------------------------------
template <int KK, int NTG>
__device__ __forceinline__ void stag_region(
    const unsigned short* __restrict__ wfrag,
    const float* __restrict__ bias,
    const unsigned short* __restrict__ actX,
    unsigned short* actY,
    f32x4 (&accX)[4][NTG], f32x4 (&accY)[4][NTG],
    const float* xstY, bool splice, int wave, int lane)
{
    const int quad = lane >> 4;
    const int l15  = lane & 15;
    constexpr int S = 4 * NTG;   // retirement slices

#pragma unroll
    for (int i = 0; i < 4; ++i) {
        const int chb = (wave * 4 + i) * 16 + quad * 4;
        const float4 b4 = *(const float4*)(bias + chb);
#pragma unroll
        for (int nt = 0; nt < NTG; ++nt)
            accX[i][nt] = f32x4{b4.x, b4.y, b4.z, b4.w};
    }

    const unsigned short* wbase = wfrag + (wave * 4 * KK * 64 + lane) * 8;

#pragma unroll
    for (int kk = 0; kk < KK; ++kk) {
        // loads first (ds + vmem), retirement VALU in their shadow, mfma last
        bf16x8 bfr[NTG];
#pragma unroll
        for (int nt = 0; nt < NTG; ++nt)
            bfr[nt] = *(const bf16x8*)(actX + (nt * 16 + l15) * LDA + kk * 32 + quad * 8);

        bf16x8 afr[4];
#pragma unroll
        for (int i = 0; i < 4; ++i)
            afr[i] = *(const bf16x8*)(wbase + (i * KK + kk) * 512);

#pragma unroll
        for (int sbase = 0; sbase < 2; ++sbase) {
            const int s = kk + sbase * 8;        // compile-time
            if (s < S && (sbase == 0 ? (kk < 8) : true)) {
                const int i  = s & 3;
                const int nt = s >> 2;
                const int chb = (wave * 4 + i) * 16 + quad * 4;
                const int pt  = nt * 16 + l15;
                float vv[4];
#pragma unroll
                for (int r = 0; r < 4; ++r)
                    vv[r] = softplus_t2(accY[i][nt][r]);
                if (splice && chb == 252) {   // ch 253..255 <- raw x
                    vv[1] = xstY[pt * 4 + 0];
                    vv[2] = xstY[pt * 4 + 1];
                    vv[3] = xstY[pt * 4 + 2];
                }
                __hip_bfloat162 p01 = __float22bfloat162_rn(float2{vv[0], vv[1]});
                __hip_bfloat162 p23 = __float22bfloat162_rn(float2{vv[2], vv[3]});
                uint2 pk;
                pk.x = *(unsigned int*)&p01;
                pk.y = *(unsigned int*)&p23;
                *(uint2*)(actY + pt * LDA + chb) = pk;
            }
        }

#pragma unroll
        for (int i = 0; i < 4; ++i)
#pragma unroll
            for (int nt = 0; nt < NTG; ++nt)
                accX[i][nt] = __builtin_amdgcn_mfma_f32_16x16x32_bf16(afr[i], bfr[nt], accX[i][nt], 0, 0, 0);
    }
}

// ---------------------------------------------------------------------------
// Layer 7 (256->8) for one 16-pt row block at row0; reduce + CSG + store.
// ---------------------------------------------------------------------------
__device__ __forceinline__ void l7_part(
    const unsigned short* act, const unsigned short* __restrict__ w7,
    const float* __restrict__ wsB, float* __restrict__ out,
    int row0, int ptg0, int npts, int lane)
{
    const int quad = lane >> 4, l15 = lane & 15;
    const float4 b4 = *(const float4*)(wsB + OFFB7 + quad * 4);  // quads>=2: zeros
    f32x4 acc = f32x4{b4.x, b4.y, b4.z, b4.w};
#pragma unroll
    for (int kk = 0; kk < 8; ++kk) {
        bf16x8 bfr = *(const bf16x8*)(act + (row0 + l15) * LDA + kk * 32 + quad * 8);
        bf16x8 afr = *(const bf16x8*)(w7 + (kk * 64 + lane) * 8);
        acc = __builtin_amdgcn_mfma_f32_16x16x32_bf16(afr, bfr, acc, 0, 0, 0);
    }
    // quad0 lanes hold ch0-3, quad1 ch4-7 for pt = row0+l15
    float u0 = __shfl(acc[0], l15 + 16);
    float u1 = __shfl(acc[1], l15 + 16);
    float u2 = __shfl(acc[2], l15 + 16);
    float u3 = __shfl(acc[3], l15 + 16);
    if (quad == 0) {
        const int ptg = ptg0 + l15;
        if (ptg < npts) {
            const float v0 = acc[0], v1 = acc[1], v2 = acc[2], v3 = acc[3];
            const float v4 = u0, v5 = u1, v6 = u2, v7 = u3;
            const float m23   = fminf(v2, v3);
            const float m67   = fmaxf(v6, v7);
            const float m4567 = fminf(fminf(v4, v5), m67);
            const float h     = fmaxf(fmaxf(v0, v1), fmaxf(m23, m4567));
            float* o = out + (long)ptg * 9;
            o[0] = h;
            o[1] = v0; o[2] = v1; o[3] = v2; o[4] = v3;
            o[5] = v4; o[6] = v5; o[7] = v6; o[8] = v7;
        }
    }
}

// ---------------------------------------------------------------------------
// Full network for one tile of 2*NTG*16 points (NTG=3 -> 96, NTG=1 -> 32),
// 4 waves, each owning 64 output channels. Two staggered in-place groups
// A (rows 0..NTG*16) and B (rest). Schedule:
//   stage; bar
//   mfma_A(0); bar
//   mfma_B(0); epi_A(0); bar
//   l=1..6:  stag[mfma_A(l) + slices of accB(l-1)]; bar
//            stag[mfma_B(l) + slices of accA(l)];   bar
//   [L7(A) || epi_B(6)]; bar;  L7(B)
// ---------------------------------------------------------------------------
template <int NTG>
__device__ __forceinline__ void run_net(
    const float* __restrict__ x, float* __restrict__ out,
    const unsigned short* __restrict__ wsW, const float* __restrict__ wsB,
    unsigned short* act, float* xst,
    int base_pt, int npts, int tid)
{
    const int wave = tid >> 6, lane = tid & 63;

    // stage x into act channels 0..2, zero-pad to 32 (K-pad for layer 0)
    for (int i = tid; i < 2 * NTG * 16 * 32; i += 256) {
        const int pt = i >> 5, ch = i & 31;
        const int ptg = base_pt + pt;
        float v = 0.0f;
        if (ch < 3 && ptg < npts) v = x[ptg * 3 + ch];
        act[pt * LDA + ch] = bf16_rne(v);
        if (ch < 4) xst[pt * 4 + ch] = (ch < 3) ? v : 0.0f;
    }
    __syncthreads();

    unsigned short* actA = act;
    unsigned short* actB = act + NTG * 16 * LDA;
    const float* xstA = xst;
    const float* xstB = xst + NTG * 16 * 4;

    f32x4 accA[4][NTG], accB[4][NTG];

    // layer 0 (KK=1, tiny): A alone, then B with serial epi_A
    mfma_group<1, NTG>(wsW + OFFW0, wsB, actA, accA, wave, lane);
    __syncthreads();
    mfma_group<1, NTG>(wsW + OFFW0, wsB, actB, accB, wave, lane);
    epi_group_full<NTG>(accA, actA, xstA, wave, lane, false);
    __syncthreads();

    // layers 1..6, two staggered regions each
#pragma unroll 1
    for (int l = 1; l <= 6; ++l) {
        const unsigned short* Wl = wsW + OFFW1 + (l - 1) * 65536;
        const float* bl = wsB + l * 256;

        // mfma_A(l) + retire accB(l-1)  (splice when l-1 == 3)
        stag_region<8, NTG>(Wl, bl, actA, actB, accA, accB, xstB, l == 4, wave, lane);
        __syncthreads();

        // mfma_B(l) + retire accA(l)    (splice when l == 3)
        stag_region<8, NTG>(Wl, bl, actB, actA, accB, accA, xstA, l == 3, wave, lane);
        __syncthreads();
    }

    // [L7(A) || epi_B(6)]: actA finalized last region; epi writes actB only.
    if (wave < NTG)
        l7_part(act, wsW + OFFW7, wsB, out, wave * 16, base_pt + wave * 16, npts, lane);
    epi_group_full<NTG>(accB, actB, xstB, wave, lane, false);
    __syncthreads();

    // L7(B)
    if (wave < NTG)
        l7_part(act, wsW + OFFW7, wsB, out,
                NTG * 16 + wave * 16, base_pt + NTG * 16 + wave * 16, npts, lane);
}

__global__ __launch_bounds__(256, 3)
void nhrep_main(const float* __restrict__ x, float* __restrict__ out,
                const unsigned short* __restrict__ wsW,
                const float* __restrict__ wsB, int npts, int nbig)
{
    __shared__ unsigned short act[96 * LDA];   // 50688 B
    __shared__ float xst[96 * 4];              // 1536 B -> 52224 B (3 blk/CU)
    const int b = blockIdx.x;
    if (b < nbig) {
        run_net<3>(x, out, wsW, wsB, act, xst, b * 96, npts, threadIdx.x);
    } else {
        run_net<1>(x, out, wsW, wsB, act, xst,
                   nbig * 96 + (b - nbig) * 32, npts, threadIdx.x);
    }
}

// ---------------------------------------------------------------------------
// Fused prepack with scale folding (proven since R4, identity k-mapping).
// Frag (mt,kk,lane,j) = scale(l,k) * W^T[mt*16+(lane&15)][kk*32+(lane>>4)*8+j]
// ---------------------------------------------------------------------------
struct PackArgs {
    const float* W[8];
    const float* b[8];
};

#define TOTAL_FRAGS 50688
#define TOTAL_BIAS  1808

__global__ void prepack_all(PackArgs args, unsigned short* __restrict__ dstW,
                            float* __restrict__ dstB)
{
    const int t = blockIdx.x * blockDim.x + threadIdx.x;
    const int FB[9]  = {0, 1024, 9216, 17408, 25600, 33792, 41984, 50176, 50688};
    const int KKs[8] = {1, 8, 8, 8, 8, 8, 8, 8};
    const int ind[8] = {3, 256, 256, 256, 256, 256, 256, 256};
    const int outd[8]= {256, 256, 256, 253, 256, 256, 256, 8};

    if (t < TOTAL_FRAGS) {
        int l = 0;
        while (t >= FB[l + 1]) ++l;
        const int f    = t - FB[l];
        const int lane = f & 63;
        const int kk   = (f >> 6) % KKs[l];
        const int mt   = f / (64 * KKs[l]);
        const int o    = mt * 16 + (lane & 15);
        const int kb   = kk * 32 + (lane >> 4) * 8;
        const float* W = args.W[l];
        const int in_d = ind[l], out_d = outd[l];

        unsigned short v[8];
#pragma unroll
        for (int j = 0; j < 8; ++j) {
            const int k = kb + j;
            float w = 0.0f;
            if (k < in_d && o < out_d) {
                float sc = 1.0f;
                if (l == 0) sc = SCALE_T2;
                else if (l == 4) sc = (k < 253) ? INV_SQRT2 : (SCALE_T2 * INV_SQRT2);
                else if (l == 7) sc = LN2_100;
                w = W[k * out_d + o] * sc;
            }
            unsigned int u = __float_as_uint(w);
            v[j] = (unsigned short)((u + 0x7FFFu + ((u >> 16) & 1u)) >> 16);
        }
        uint4 p;
        p.x = (unsigned int)v[0] | ((unsigned int)v[1] << 16);
        p.y = (unsigned int)v[2] | ((unsigned int)v[3] << 16);
        p.z = (unsigned int)v[4] | ((unsigned int)v[5] << 16);
        p.w = (unsigned int)v[6] | ((unsigned int)v[7] << 16);
        *(uint4*)(dstW + (long)t * 8) = p;
    } else if (t < TOTAL_FRAGS + TOTAL_BIAS) {
        const int u = t - TOTAL_FRAGS;
        const int l = (u < 1792) ? (u >> 8) : 7;
        const int idx = (l < 7) ? (u & 255) : (u - 1792);
        const float sc = (l < 7) ? SCALE_T2 : 1.0f;   // b7 stays in output units
        dstB[u] = (idx < outd[l]) ? args.b[l][idx] * sc : 0.0f;
    }
}

extern "C" void kernel_launch(void* const* d_in, const int* in_sizes, int n_in,
                              void* d_out, int out_size, void* d_ws, size_t ws_size,
                              hipStream_t stream)
{
    const float* x = (const float*)d_in[0];
    unsigned short* wsW = (unsigned short*)d_ws;
    float* wsB = (float*)((char*)d_ws + WSB_BYTE_OFF);

    PackArgs pa;
    for (int l = 0; l < 8; ++l) {
        pa.W[l] = (const float*)d_in[1 + 2 * l];
        pa.b[l] = (const float*)d_in[2 + 2 * l];
    }
    const int ptot = TOTAL_FRAGS + TOTAL_BIAS;
    prepack_all<<<(ptot + 255) / 256, 256, 0, stream>>>(pa, wsW, wsB);

    const int npts = in_sizes[0] / 3;            // 100000
    // Mixed grid: 96-pt blocks for the bulk, 32-pt blocks for the drain tail.
    int nbig, nsmall;
    const int tail_pts = 16384;
    if (npts > tail_pts) {
        nbig = (npts - tail_pts + 95) / 96;      // 871
        const int base_small = nbig * 96;
        nsmall = (npts - base_small + 31) / 32;  // 512
    } else {
        nbig = 0;
        nsmall = (npts + 31) / 32;
    }
    nhrep_main<<<nbig + nsmall, 256, 0, stream>>>(x, (float*)d_out, wsW, wsB,
                                                  npts, nbig);
}

// Round 5
// 182.988 us; speedup vs baseline: 1.6192x; 1.6192x over previous
//
#include <hip/hip_runtime.h>
#include <hip/hip_bf16.h>

// ---------------------------------------------------------------------------
// NHRepNet fused forward, Round 19: R17 geometry, compiler-budgeted prefetch.
//
// Established (R1-R18):
//  - R17 (96-pt, kk-sliced A/B stagger, 8 waves x 32ch): 103.4us, Mfma+VALU
//    87%. Interleave PROVEN (+12 vs R14's phase-serial 115). Carried ~6MB
//    spill tax from the explicit depth-1 afr prefetch (WRITE 9.9 vs 3.5MB).
//  - R18 (Gch=4, dual acc[4][3]=96 regs): catastrophic spill (WRITE 460MB,
//    222us). LESSON: dual-acc = 2x per-group acc; Gch=4+stagger needs >=96
//    acc regs -> no tier fits. Gch=4 direction CLOSED (with R13's A-traffic
//    half of the tradeoff).
//  - Streams @103us: VALU ~54us (trans-heavy softplus, exp/log at 1/4 rate),
//    LDS-B ~35-40us (12cyc/b128 incl. inherent wave64 multi-bank), MFMA ~35us,
//    A 1.56GB L2. Critical path after de-spill = VALU.
//
// R19 = R17 with in-loop afr loads (R16's proven-clean order): bfr ds_reads ->
// afr loads -> retirement slice VALU in their shadow -> 6 MFMAs. Live set
// 48 dual-acc + 12 bfr + 8 afr + ~45 misc ~= 118 <= 128 tier (512thr, 2blk/CU).
// Compiler may pipeline afr within ITS budget (forcing it via source is what
// spilled). Gate #1: WRITE <= 4MB. Target: 94-99us.
// ---------------------------------------------------------------------------

using bf16x8 = __attribute__((ext_vector_type(8))) __bf16;
using f32x4  = __attribute__((ext_vector_type(4))) float;

#define LDA 264   // padded activation row stride (bf16)

#define OFFW0 0
#define OFFW1 8192
#define OFFW7 401408
#define WSB_BYTE_OFF 811008   // fp32 bias region
#define OFFB7 1792            // L0..L6 at l*256; L7 at 1792 (16 floats, padded)

#define SCALE_T2 144.26950408889634f      // 100*log2(e)
#define INV_SQRT2 0.70710678118654752f
#define LN2_100 0.0069314718055994531f    // ln2/100

__device__ __forceinline__ float fast_exp2(float x) {
#if __has_builtin(__builtin_amdgcn_exp2f)
    return __builtin_amdgcn_exp2f(x);
#else
    return exp2f(x);
#endif
}
__device__ __forceinline__ float fast_log2(float x) {
#if __has_builtin(__builtin_amdgcn_logf)
    return __builtin_amdgcn_logf(x);
#else
    return log2f(x);
#endif
}

// a2 = max(t2,0) + log2(1 + 2^-|t2|)   (t2-domain; scales folded into weights)
__device__ __forceinline__ float softplus_t2(float t2) {
    float e = fast_exp2(-fabsf(t2));
    float l = fast_log2(1.0f + e);
    return fmaxf(t2, 0.0f) + l;
}

__device__ __forceinline__ unsigned short bf16_rne(float f) {
    unsigned int u = __float_as_uint(f);
    unsigned int r = u + 0x7FFFu + ((u >> 16) & 1u);
    return (unsigned short)(r >> 16);
}

// ---------------------------------------------------------------------------
// Plain MFMA half (layer 0 only, KK=1). Wave owns ch [wave*32, wave*32+32).
// ---------------------------------------------------------------------------
template <int KK, int NTG>
__device__ __forceinline__ void mfma_group(
    const unsigned short* __restrict__ wfrag,
    const float* __restrict__ bias,
    const unsigned short* act,
    f32x4 (&acc)[2][NTG], int wave, int lane)
{
    const int quad = lane >> 4;
    const int l15  = lane & 15;

#pragma unroll
    for (int i = 0; i < 2; ++i) {
        const int chb = (wave * 2 + i) * 16 + quad * 4;
        const float4 b4 = *(const float4*)(bias + chb);
#pragma unroll
        for (int nt = 0; nt < NTG; ++nt)
            acc[i][nt] = f32x4{b4.x, b4.y, b4.z, b4.w};
    }

    const unsigned short* wbase = wfrag + (wave * 2 * KK * 64 + lane) * 8;

#pragma unroll
    for (int kk = 0; kk < KK; ++kk) {
        bf16x8 bfr[NTG];
#pragma unroll
        for (int nt = 0; nt < NTG; ++nt)
            bfr[nt] = *(const bf16x8*)(act + (nt * 16 + l15) * LDA + kk * 32 + quad * 8);
#pragma unroll
        for (int i = 0; i < 2; ++i) {
            bf16x8 afr = *(const bf16x8*)(wbase + (i * KK + kk) * 512);
#pragma unroll
            for (int nt = 0; nt < NTG; ++nt)
                acc[i][nt] = __builtin_amdgcn_mfma_f32_16x16x32_bf16(afr, bfr[nt], acc[i][nt], 0, 0, 0);
        }
    }
}

// Full epilogue of a group (used where no mfma to hide under).
template <int NTG>
__device__ __forceinline__ void epi_group_full(
    f32x4 (&acc)[2][NTG], unsigned short* act, const float* xst,
    int wave, int lane, bool splice)
{
    const int quad = lane >> 4;
    const int l15  = lane & 15;
#pragma unroll
    for (int i = 0; i < 2; ++i) {
        const int chb = (wave * 2 + i) * 16 + quad * 4;
#pragma unroll
        for (int nt = 0; nt < NTG; ++nt) {
            const int pt = nt * 16 + l15;
            float vv[4];
#pragma unroll
            for (int r = 0; r < 4; ++r)
                vv[r] = softplus_t2(acc[i][nt][r]);
            if (splice && chb == 252) {
                vv[1] = xst[pt * 4 + 0];
                vv[2] = xst[pt * 4 + 1];
                vv[3] = xst[pt * 4 + 2];
            }
            __hip_bfloat162 p01 = __float22bfloat162_rn(float2{vv[0], vv[1]});
            __hip_bfloat162 p23 = __float22bfloat162_rn(float2{vv[2], vv[3]});
            uint2 pk;
            pk.x = *(unsigned int*)&p01;
            pk.y = *(unsigned int*)&p23;
            *(uint2*)(act + pt * LDA + chb) = pk;
        }
    }
}

// ---------------------------------------------------------------------------
// Staggered region: build accX = W.actX + b while retiring accY (other
// group's previous-layer preacts) one slice per kk step (6 slices, kk 0..5).
// Order per kk: bfr ds_reads -> afr loads -> slice VALU (in load shadow) ->
// 6 MFMAs. No forced prefetch: compiler pipelines within its reg budget.
// ---------------------------------------------------------------------------
template <int KK, int NTG>
__device__ __forceinline__ void stag_region(
    const unsigned short* __restrict__ wfrag,
    const float* __restrict__ bias,
    const unsigned short* __restrict__ actX,
    unsigned short* actY,
    f32x4 (&accX)[2][NTG], f32x4 (&accY)[2][NTG],
    const float* xstY, bool splice, int wave, int lane)
{
    const int quad = lane >> 4;
    const int l15  = lane & 15;

#pragma unroll
    for (int i = 0; i < 2; ++i) {
        const int chb = (wave * 2 + i) * 16 + quad * 4;
        const float4 b4 = *(const float4*)(bias + chb);
#pragma unroll
        for (int nt = 0; nt < NTG; ++nt)
            accX[i][nt] = f32x4{b4.x, b4.y, b4.z, b4.w};
    }

    const unsigned short* wbase = wfrag + (wave * 2 * KK * 64 + lane) * 8;

#pragma unroll
    for (int kk = 0; kk < KK; ++kk) {
        bf16x8 bfr[NTG];
#pragma unroll
        for (int nt = 0; nt < NTG; ++nt)
            bfr[nt] = *(const bf16x8*)(actX + (nt * 16 + l15) * LDA + kk * 32 + quad * 8);

        bf16x8 a0 = *(const bf16x8*)(wbase + kk * 512);
        bf16x8 a1 = *(const bf16x8*)(wbase + (KK + kk) * 512);

        if (kk < 2 * NTG) {   // one retired slice of group Y (compile-time idx)
            const int i  = kk & 1;       // constant under full unroll
            const int nt = kk >> 1;
            const int chb = (wave * 2 + i) * 16 + quad * 4;
            const int pt  = nt * 16 + l15;
            float vv[4];
#pragma unroll
            for (int r = 0; r < 4; ++r)
                vv[r] = softplus_t2(accY[i][nt][r]);
            if (splice && chb == 252) {   // ch 253..255 <- raw x
                vv[1] = xstY[pt * 4 + 0];
                vv[2] = xstY[pt * 4 + 1];
                vv[3] = xstY[pt * 4 + 2];
            }
            __hip_bfloat162 p01 = __float22bfloat162_rn(float2{vv[0], vv[1]});
            __hip_bfloat162 p23 = __float22bfloat162_rn(float2{vv[2], vv[3]});
            uint2 pk;
            pk.x = *(unsigned int*)&p01;
            pk.y = *(unsigned int*)&p23;
            *(uint2*)(actY + pt * LDA + chb) = pk;
        }

#pragma unroll
        for (int nt = 0; nt < NTG; ++nt)
            accX[0][nt] = __builtin_amdgcn_mfma_f32_16x16x32_bf16(a0, bfr[nt], accX[0][nt], 0, 0, 0);
#pragma unroll
        for (int nt = 0; nt < NTG; ++nt)
            accX[1][nt] = __builtin_amdgcn_mfma_f32_16x16x32_bf16(a1, bfr[nt], accX[1][nt], 0, 0, 0);
    }
}

// ---------------------------------------------------------------------------
// Layer 7 (256->8) for one 16-pt row block at row0; reduce + CSG + store.
// ---------------------------------------------------------------------------
__device__ __forceinline__ void l7_part(
    const unsigned short* act, const unsigned short* __restrict__ w7,
    const float* __restrict__ wsB, float* __restrict__ out,
    int row0, int ptg0, int npts, int lane)
{
    const int quad = lane >> 4, l15 = lane & 15;
    const float4 b4 = *(const float4*)(wsB + OFFB7 + quad * 4);  // quads>=2: zeros
    f32x4 acc = f32x4{b4.x, b4.y, b4.z, b4.w};
#pragma unroll
    for (int kk = 0; kk < 8; ++kk) {
        bf16x8 bfr = *(const bf16x8*)(act + (row0 + l15) * LDA + kk * 32 + quad * 8);
        bf16x8 afr = *(const bf16x8*)(w7 + (kk * 64 + lane) * 8);
        acc = __builtin_amdgcn_mfma_f32_16x16x32_bf16(afr, bfr, acc, 0, 0, 0);
    }
    // quad0 lanes hold ch0-3, quad1 ch4-7 for pt = row0+l15
    float u0 = __shfl(acc[0], l15 + 16);
    float u1 = __shfl(acc[1], l15 + 16);
    float u2 = __shfl(acc[2], l15 + 16);
    float u3 = __shfl(acc[3], l15 + 16);
    if (quad == 0) {
        const int ptg = ptg0 + l15;
        if (ptg < npts) {
            const float v0 = acc[0], v1 = acc[1], v2 = acc[2], v3 = acc[3];
            const float v4 = u0, v5 = u1, v6 = u2, v7 = u3;
            const float m23   = fminf(v2, v3);
            const float m67   = fmaxf(v6, v7);
            const float m4567 = fminf(fminf(v4, v5), m67);
            const float h     = fmaxf(fmaxf(v0, v1), fmaxf(m23, m4567));
            float* o = out + (long)ptg * 9;
            o[0] = h;
            o[1] = v0; o[2] = v1; o[3] = v2; o[4] = v3;
            o[5] = v4; o[6] = v5; o[7] = v6; o[8] = v7;
        }
    }
}

// ---------------------------------------------------------------------------
// Full network for one tile of 2*NTG*16 points (NTG=3 -> 96, NTG=1 -> 32),
// two staggered in-place groups A (rows 0..NTG*16) and B (rest). Schedule:
//   stage; bar
//   mfma_A(0); bar
//   mfma_B(0); epi_A(0); bar
//   l=1..6:  stag[mfma_A(l) + slices of accB(l-1)]; bar
//            stag[mfma_B(l) + slices of accA(l)];   bar
//   [L7(A) || epi_B(6)]; bar;  L7(B)
// ---------------------------------------------------------------------------
template <int NTG>
__device__ __forceinline__ void run_net(
    const float* __restrict__ x, float* __restrict__ out,
    const unsigned short* __restrict__ wsW, const float* __restrict__ wsB,
    unsigned short* act, float* xst,
    int base_pt, int npts, int tid)
{
    const int wave = tid >> 6, lane = tid & 63;

    // stage x into act channels 0..2, zero-pad to 32 (K-pad for layer 0)
    for (int i = tid; i < 2 * NTG * 16 * 32; i += 512) {
        const int pt = i >> 5, ch = i & 31;
        const int ptg = base_pt + pt;
        float v = 0.0f;
        if (ch < 3 && ptg < npts) v = x[ptg * 3 + ch];
        act[pt * LDA + ch] = bf16_rne(v);
        if (ch < 4) xst[pt * 4 + ch] = (ch < 3) ? v : 0.0f;
    }
    __syncthreads();

    unsigned short* actA = act;
    unsigned short* actB = act + NTG * 16 * LDA;
    const float* xstA = xst;
    const float* xstB = xst + NTG * 16 * 4;

    f32x4 accA[2][NTG], accB[2][NTG];

    // layer 0 (KK=1, tiny): A alone, then B with serial epi_A
    mfma_group<1, NTG>(wsW + OFFW0, wsB, actA, accA, wave, lane);
    __syncthreads();
    mfma_group<1, NTG>(wsW + OFFW0, wsB, actB, accB, wave, lane);
    epi_group_full<NTG>(accA, actA, xstA, wave, lane, false);
    __syncthreads();

    // layers 1..6, two staggered regions each
#pragma unroll 1
    for (int l = 1; l <= 6; ++l) {
        const unsigned short* Wl = wsW + OFFW1 + (l - 1) * 65536;
        const float* bl = wsB + l * 256;

        // mfma_A(l) + retire accB(l-1)  (splice when l-1 == 3)
        stag_region<8, NTG>(Wl, bl, actA, actB, accA, accB, xstB, l == 4, wave, lane);
        __syncthreads();

        // mfma_B(l) + retire accA(l)    (splice when l == 3)
        stag_region<8, NTG>(Wl, bl, actB, actA, accB, accA, xstA, l == 3, wave, lane);
        __syncthreads();
    }

    // [L7(A) || epi_B(6)]: actA finalized last region; epi writes actB only.
    if (wave < NTG)
        l7_part(act, wsW + OFFW7, wsB, out, wave * 16, base_pt + wave * 16, npts, lane);
    epi_group_full<NTG>(accB, actB, xstB, wave, lane, false);
    __syncthreads();

    // L7(B)
    if (wave < NTG)
        l7_part(act, wsW + OFFW7, wsB, out,
                NTG * 16 + wave * 16, base_pt + NTG * 16 + wave * 16, npts, lane);
}

__global__ __launch_bounds__(512, 4)
void nhrep_main(const float* __restrict__ x, float* __restrict__ out,
                const unsigned short* __restrict__ wsW,
                const float* __restrict__ wsB, int npts, int nbig)
{
    __shared__ unsigned short act[96 * LDA];   // 50688 B
    __shared__ float xst[96 * 4];              // 1536 B -> 52224 B total
    const int b = blockIdx.x;
    if (b < nbig) {
        run_net<3>(x, out, wsW, wsB, act, xst, b * 96, npts, threadIdx.x);
    } else {
        run_net<1>(x, out, wsW, wsB, act, xst,
                   nbig * 96 + (b - nbig) * 32, npts, threadIdx.x);
    }
}

// ---------------------------------------------------------------------------
// Fused prepack with scale folding (proven since R4, identity k-mapping).
// Frag (mt,kk,lane,j) = scale(l,k) * W^T[mt*16+(lane&15)][kk*32+(lane>>4)*8+j]
// ---------------------------------------------------------------------------
struct PackArgs {
    const float* W[8];
    const float* b[8];
};

#define TOTAL_FRAGS 50688
#define TOTAL_BIAS  1808

__global__ void prepack_all(PackArgs args, unsigned short* __restrict__ dstW,
                            float* __restrict__ dstB)
{
    const int t = blockIdx.x * blockDim.x + threadIdx.x;
    const int FB[9]  = {0, 1024, 9216, 17408, 25600, 33792, 41984, 50176, 50688};
    const int KKs[8] = {1, 8, 8, 8, 8, 8, 8, 8};
    const int ind[8] = {3, 256, 256, 256, 256, 256, 256, 256};
    const int outd[8]= {256, 256, 256, 253, 256, 256, 256, 8};

    if (t < TOTAL_FRAGS) {
        int l = 0;
        while (t >= FB[l + 1]) ++l;
        const int f    = t - FB[l];
        const int lane = f & 63;
        const int kk   = (f >> 6) % KKs[l];
        const int mt   = f / (64 * KKs[l]);
        const int o    = mt * 16 + (lane & 15);
        const int kb   = kk * 32 + (lane >> 4) * 8;
        const float* W = args.W[l];
        const int in_d = ind[l], out_d = outd[l];

        unsigned short v[8];
#pragma unroll
        for (int j = 0; j < 8; ++j) {
            const int k = kb + j;
            float w = 0.0f;
            if (k < in_d && o < out_d) {
                float sc = 1.0f;
                if (l == 0) sc = SCALE_T2;
                else if (l == 4) sc = (k < 253) ? INV_SQRT2 : (SCALE_T2 * INV_SQRT2);
                else if (l == 7) sc = LN2_100;
                w = W[k * out_d + o] * sc;
            }
            unsigned int u = __float_as_uint(w);
            v[j] = (unsigned short)((u + 0x7FFFu + ((u >> 16) & 1u)) >> 16);
        }
        uint4 p;
        p.x = (unsigned int)v[0] | ((unsigned int)v[1] << 16);
        p.y = (unsigned int)v[2] | ((unsigned int)v[3] << 16);
        p.z = (unsigned int)v[4] | ((unsigned int)v[5] << 16);
        p.w = (unsigned int)v[6] | ((unsigned int)v[7] << 16);
        *(uint4*)(dstW + (long)t * 8) = p;
    } else if (t < TOTAL_FRAGS + TOTAL_BIAS) {
        const int u = t - TOTAL_FRAGS;
        const int l = (u < 1792) ? (u >> 8) : 7;
        const int idx = (l < 7) ? (u & 255) : (u - 1792);
        const float sc = (l < 7) ? SCALE_T2 : 1.0f;   // b7 stays in output units
        dstB[u] = (idx < outd[l]) ? args.b[l][idx] * sc : 0.0f;
    }
}

extern "C" void kernel_launch(void* const* d_in, const int* in_sizes, int n_in,
                              void* d_out, int out_size, void* d_ws, size_t ws_size,
                              hipStream_t stream)
{
    const float* x = (const float*)d_in[0];
    unsigned short* wsW = (unsigned short*)d_ws;
    float* wsB = (float*)((char*)d_ws + WSB_BYTE_OFF);

    PackArgs pa;
    for (int l = 0; l < 8; ++l) {
        pa.W[l] = (const float*)d_in[1 + 2 * l];
        pa.b[l] = (const float*)d_in[2 + 2 * l];
    }
    const int ptot = TOTAL_FRAGS + TOTAL_BIAS;
    prepack_all<<<(ptot + 255) / 256, 256, 0, stream>>>(pa, wsW, wsB);

    const int npts = in_sizes[0] / 3;            // 100000
    // Mixed grid: 96-pt blocks for the bulk, 32-pt blocks for the drain tail.
    int nbig, nsmall;
    const int tail_pts = 16384;
    if (npts > tail_pts) {
        nbig = (npts - tail_pts + 95) / 96;      // 871
        const int base_small = nbig * 96;
        nsmall = (npts - base_small + 31) / 32;  // 512
    } else {
        nbig = 0;
        nsmall = (npts + 31) / 32;
    }
    nhrep_main<<<nbig + nsmall, 512, 0, stream>>>(x, (float*)d_out, wsW, wsB,
                                                  npts, nbig);
}